// Round 3
// baseline (144.996 us; speedup 1.0000x reference)
//
#include <hip/hip_runtime.h>

#define NROWS 16384
#define DIM   1024          // floats per row
#define F4_PER_ROW 256      // DIM/4
#define MARGIN_F 1.0f
#define EPS_F 1e-6f

// One WAVE per row, 4 rows per 256-thread block. ALL 12 float4 loads are
// issued before any use (empty asm memory fence stops the compiler from
// sinking loads to their first use — the round-1/2 regression: regalloc
// dropped to 32 VGPR and serialized the loads). Then ONE Gram pass:
//   sum_p = si^2*ni + sp^2*np - 2*si*sp*dot_ip + 2*eps*(si*Sa - sp*Sb) + D*eps^2
// (exact expansion of sum((a*si - b*sp + eps)^2); absmax 0.0 in r1/r2).
// Per-block partial -> one device-scope atomicAdd; no second kernel.
__global__ __launch_bounds__(256) void row_loss_kernel(
    const float* __restrict__ emb,
    const int*   __restrict__ pos_idx,
    const int*   __restrict__ neg_idx,
    float*       __restrict__ out)
{
    const int tid  = threadIdx.x;
    const int lane = tid & 63;
    const int wid  = tid >> 6;
    const int row  = blockIdx.x * 4 + wid;

    const int p = pos_idx[row];   // wave-uniform -> scalar loads
    const int n = neg_idx[row];

    const float4* xi = (const float4*)(emb + (size_t)row * DIM) + lane;
    const float4* xp = (const float4*)(emb + (size_t)p   * DIM) + lane;
    const float4* xn = (const float4*)(emb + (size_t)n   * DIM) + lane;

    // --- issue all 12 independent 16B loads (interleaved across streams) ---
    float4 a[4], b[4], c[4];
    #pragma unroll
    for (int j = 0; j < 4; ++j) {
        a[j] = xi[64 * j];
        b[j] = xp[64 * j];
        c[j] = xn[64 * j];
    }
    // fence: loads may not sink past this point; waits still land at first use
    asm volatile("" ::: "memory");

    // --- single Gram pass ---
    float ni = 0.f, np_ = 0.f, nn = 0.f;   // squared norms
    float dip = 0.f, din = 0.f;            // dot(a,b), dot(a,c)
    float sa = 0.f, sb = 0.f, sc = 0.f;    // element sums (eps cross-terms)
    #pragma unroll
    for (int j = 0; j < 4; ++j) {
        const float4 A = a[j], B = b[j], C = c[j];
        ni  = fmaf(A.x,A.x,ni);  ni  = fmaf(A.y,A.y,ni);  ni  = fmaf(A.z,A.z,ni);  ni  = fmaf(A.w,A.w,ni);
        np_ = fmaf(B.x,B.x,np_); np_ = fmaf(B.y,B.y,np_); np_ = fmaf(B.z,B.z,np_); np_ = fmaf(B.w,B.w,np_);
        nn  = fmaf(C.x,C.x,nn);  nn  = fmaf(C.y,C.y,nn);  nn  = fmaf(C.z,C.z,nn);  nn  = fmaf(C.w,C.w,nn);
        dip = fmaf(A.x,B.x,dip); dip = fmaf(A.y,B.y,dip); dip = fmaf(A.z,B.z,dip); dip = fmaf(A.w,B.w,dip);
        din = fmaf(A.x,C.x,din); din = fmaf(A.y,C.y,din); din = fmaf(A.z,C.z,din); din = fmaf(A.w,C.w,din);
        sa += (A.x + A.y) + (A.z + A.w);
        sb += (B.x + B.y) + (B.z + B.w);
        sc += (C.x + C.y) + (C.z + C.w);
    }

    // one butterfly over 8 independent values
    #pragma unroll
    for (int m = 1; m < 64; m <<= 1) {
        ni  += __shfl_xor(ni,  m, 64);
        np_ += __shfl_xor(np_, m, 64);
        nn  += __shfl_xor(nn,  m, 64);
        dip += __shfl_xor(dip, m, 64);
        din += __shfl_xor(din, m, 64);
        sa  += __shfl_xor(sa,  m, 64);
        sb  += __shfl_xor(sb,  m, 64);
        sc  += __shfl_xor(sc,  m, 64);
    }

    __shared__ float sm[4];
    if (lane == 0) {
        const float si = 1.0f / fmaxf(sqrtf(ni),  EPS_F);
        const float sp = 1.0f / fmaxf(sqrtf(np_), EPS_F);
        const float sn = 1.0f / fmaxf(sqrtf(nn),  EPS_F);
        const float de2 = (float)DIM * EPS_F * EPS_F;

        float sum_p = fmaf(si * si, ni, fmaf(sp * sp, np_, -2.f * si * sp * dip))
                    + 2.f * EPS_F * (si * sa - sp * sb) + de2;
        float sum_n = fmaf(si * si, ni, fmaf(sn * sn, nn, -2.f * si * sn * din))
                    + 2.f * EPS_F * (si * sa - sn * sc) + de2;

        float d_pos = sqrtf(fmaxf(sum_p, 0.f)) + EPS_F;
        float d_neg = sqrtf(fmaxf(sum_n, 0.f)) + EPS_F;
        float mq    = fmaxf(MARGIN_F - d_neg, EPS_F);
        sm[wid] = fmaf(d_pos, d_pos, mq * mq);
    }
    __syncthreads();
    if (tid == 0)
        atomicAdd(out, ((sm[0] + sm[1]) + (sm[2] + sm[3])) * (1.0f / (2.0f * (float)NROWS)));
}

extern "C" void kernel_launch(void* const* d_in, const int* in_sizes, int n_in,
                              void* d_out, int out_size, void* d_ws, size_t ws_size,
                              hipStream_t stream) {
    const float* emb = (const float*)d_in[0];
    // d_in[1] = labels (unused by the loss itself)
    const int* pos = (const int*)d_in[2];
    const int* neg = (const int*)d_in[3];

    float* out = (float*)d_out;
    hipMemsetAsync(out, 0, sizeof(float), stream);   // graph-capturable memset node

    row_loss_kernel<<<NROWS / 4, 256, 0, stream>>>(emb, pos, neg, out);
}

// Round 4
// 113.168 us; speedup vs baseline: 1.2812x; 1.2812x over previous
//
#include <hip/hip_runtime.h>

#define NROWS 16384
#define DIM   1024          // floats per row
#define F4_PER_ROW 256      // DIM/4
#define MARGIN_F 1.0f
#define EPS_F 1e-6f

typedef float f32x4 __attribute__((ext_vector_type(4)));

// One WAVE per row, 4 rows per 256-thread block. All 12 float4 loads issued
// up-front; a SINGLE asm with twelve "+v" float4 operands forces all 12
// results to materialize at one point (12 global_load_dwordx4 in flight, one
// s_waitcnt). Round-3 lesson: a bare "memory" fence doesn't stop the FMAs
// being hoisted up between loads (VGPR=36 -> serialized); twelve separate
// asms would be volatile-ordered and re-serialize; ONE asm is the fix.
// Single Gram pass (exact eps expansion, absmax 0.0 in r1-r3):
//   sum_p = si^2*ni + sp^2*np - 2*si*sp*dot_ip + 2*eps*(si*Sa - sp*Sb) + D*eps^2
// Per-block partial to workspace; NO same-address atomics (round-3 lesson:
// 4096 device-scope atomicAdds to one address cost ~+35 us serialized).
__global__ __launch_bounds__(256) void row_loss_kernel(
    const float* __restrict__ emb,
    const int*   __restrict__ pos_idx,
    const int*   __restrict__ neg_idx,
    float*       __restrict__ block_part)
{
    const int tid  = threadIdx.x;
    const int lane = tid & 63;
    const int wid  = tid >> 6;
    const int row  = blockIdx.x * 4 + wid;

    const int p = pos_idx[row];   // wave-uniform -> scalar loads
    const int n = neg_idx[row];

    const f32x4* xi = (const f32x4*)(emb + (size_t)row * DIM) + lane;
    const f32x4* xp = (const f32x4*)(emb + (size_t)p   * DIM) + lane;
    const f32x4* xn = (const f32x4*)(emb + (size_t)n   * DIM) + lane;

    // --- issue all 12 independent 16B loads ---
    f32x4 a0 = xi[0], a1 = xi[64], a2 = xi[128], a3 = xi[192];
    f32x4 b0 = xp[0], b1 = xp[64], b2 = xp[128], b3 = xp[192];
    f32x4 c0 = xn[0], c1 = xn[64], c2 = xn[128], c3 = xn[192];

    // single materialization point: all 12 loads must be complete here,
    // so the compiler issues them all before one waitcnt (max MLP).
    asm volatile("" : "+v"(a0), "+v"(a1), "+v"(a2), "+v"(a3),
                      "+v"(b0), "+v"(b1), "+v"(b2), "+v"(b3),
                      "+v"(c0), "+v"(c1), "+v"(c2), "+v"(c3));

    // --- single Gram pass (register-resident) ---
    float ni = 0.f, np_ = 0.f, nn = 0.f;   // squared norms
    float dip = 0.f, din = 0.f;            // dot(a,b), dot(a,c)
    float sa = 0.f, sb = 0.f, sc = 0.f;    // element sums (eps cross-terms)
    #define ACC(A,B,C) \
        ni  = fmaf(A.x,A.x,ni);  ni  = fmaf(A.y,A.y,ni);  ni  = fmaf(A.z,A.z,ni);  ni  = fmaf(A.w,A.w,ni);  \
        np_ = fmaf(B.x,B.x,np_); np_ = fmaf(B.y,B.y,np_); np_ = fmaf(B.z,B.z,np_); np_ = fmaf(B.w,B.w,np_); \
        nn  = fmaf(C.x,C.x,nn);  nn  = fmaf(C.y,C.y,nn);  nn  = fmaf(C.z,C.z,nn);  nn  = fmaf(C.w,C.w,nn);  \
        dip = fmaf(A.x,B.x,dip); dip = fmaf(A.y,B.y,dip); dip = fmaf(A.z,B.z,dip); dip = fmaf(A.w,B.w,dip); \
        din = fmaf(A.x,C.x,din); din = fmaf(A.y,C.y,din); din = fmaf(A.z,C.z,din); din = fmaf(A.w,C.w,din); \
        sa += (A.x + A.y) + (A.z + A.w);   \
        sb += (B.x + B.y) + (B.z + B.w);   \
        sc += (C.x + C.y) + (C.z + C.w);
    ACC(a0,b0,c0) ACC(a1,b1,c1) ACC(a2,b2,c2) ACC(a3,b3,c3)
    #undef ACC

    // one butterfly over 8 independent values
    #pragma unroll
    for (int m = 1; m < 64; m <<= 1) {
        ni  += __shfl_xor(ni,  m, 64);
        np_ += __shfl_xor(np_, m, 64);
        nn  += __shfl_xor(nn,  m, 64);
        dip += __shfl_xor(dip, m, 64);
        din += __shfl_xor(din, m, 64);
        sa  += __shfl_xor(sa,  m, 64);
        sb  += __shfl_xor(sb,  m, 64);
        sc  += __shfl_xor(sc,  m, 64);
    }

    __shared__ float sm[4];
    if (lane == 0) {
        const float si = 1.0f / fmaxf(sqrtf(ni),  EPS_F);
        const float sp = 1.0f / fmaxf(sqrtf(np_), EPS_F);
        const float sn = 1.0f / fmaxf(sqrtf(nn),  EPS_F);
        const float de2 = (float)DIM * EPS_F * EPS_F;

        float sum_p = fmaf(si * si, ni, fmaf(sp * sp, np_, -2.f * si * sp * dip))
                    + 2.f * EPS_F * (si * sa - sp * sb) + de2;
        float sum_n = fmaf(si * si, ni, fmaf(sn * sn, nn, -2.f * si * sn * din))
                    + 2.f * EPS_F * (si * sa - sn * sc) + de2;

        float d_pos = sqrtf(fmaxf(sum_p, 0.f)) + EPS_F;
        float d_neg = sqrtf(fmaxf(sum_n, 0.f)) + EPS_F;
        float mq    = fmaxf(MARGIN_F - d_neg, EPS_F);
        sm[wid] = fmaf(d_pos, d_pos, mq * mq);
    }
    __syncthreads();
    if (tid == 0)
        block_part[blockIdx.x] = (sm[0] + sm[1]) + (sm[2] + sm[3]);
}

// 4096 block partials -> scalar. One block, 256 threads, 16 KiB read.
__global__ __launch_bounds__(256) void final_reduce_kernel(
    const float* __restrict__ part,
    float*       __restrict__ out)
{
    const int tid = threadIdx.x;
    const f32x4* p4 = (const f32x4*)part;   // 1024 float4
    float s = 0.f;
    #pragma unroll
    for (int j = 0; j < 4; ++j) {
        f32x4 v = p4[tid + 256 * j];
        s += (v.x + v.y) + (v.z + v.w);
    }
    #pragma unroll
    for (int m = 1; m < 64; m <<= 1) s += __shfl_xor(s, m, 64);

    __shared__ float sm[4];
    if ((tid & 63) == 0) sm[tid >> 6] = s;
    __syncthreads();
    if (tid == 0)
        out[0] = ((sm[0] + sm[1]) + (sm[2] + sm[3])) * (1.0f / (2.0f * (float)NROWS));
}

extern "C" void kernel_launch(void* const* d_in, const int* in_sizes, int n_in,
                              void* d_out, int out_size, void* d_ws, size_t ws_size,
                              hipStream_t stream) {
    const float* emb = (const float*)d_in[0];
    // d_in[1] = labels (unused by the loss itself)
    const int* pos = (const int*)d_in[2];
    const int* neg = (const int*)d_in[3];

    float* parts = (float*)d_ws;           // 4096 floats of scratch
    float* out   = (float*)d_out;

    row_loss_kernel<<<NROWS / 4, 256, 0, stream>>>(emb, pos, neg, parts);
    final_reduce_kernel<<<1, 256, 0, stream>>>(parts, out);
}